// Round 14
// baseline (227.136 us; speedup 1.0000x reference)
//
#include <hip/hip_runtime.h>
#include <hip/hip_bf16.h>

#define SEQ 512
#define EMB 256
#define NHEAD 8
#define HD 32

using bf16x8 = __attribute__((ext_vector_type(8))) short;
using f32x4  = __attribute__((ext_vector_type(4))) float;

static __device__ __forceinline__ unsigned short f2bf(float x) {
    union { float f; unsigned int u; } v; v.f = x;
    unsigned int r = v.u + 0x7FFFu + ((v.u >> 16) & 1u);
    return (unsigned short)(r >> 16);
}
static __device__ __forceinline__ float bf2f(unsigned short v) {
    union { unsigned int u; float f; } w; w.u = ((unsigned int)v) << 16; return w.f;
}

// ---------------- zfill: zero the strictly-future 64-aligned groups of attn.
// Partition per (b,h): strip s (rows 64s..64s+63) zeroes cols 64(s+1)..512,
// i.e. (7-s) tiles of 64x64. 28 tiles/bh, 7168 tiles total, 4 tiles per idx,
// idx in [0,1792). Exactly the groups attnW skips.
static __device__ __forceinline__ void zfill_work(int idx, int t,
                                                  float* __restrict__ attn)
{
    const f32x4 z4 = (f32x4){0.f, 0.f, 0.f, 0.f};
    #pragma unroll
    for (int i = 0; i < 4; i++) {
        int ti = idx * 4 + i;            // 0..7167
        int bh = ti / 28;
        int tt = ti - bh * 28;
        int s = 0, pre = 0;
        #pragma unroll
        for (int ss = 0; ss < 6; ss++) {
            int cnt = 7 - s;
            bool adv = tt >= pre + cnt;
            pre += adv ? cnt : 0;
            s   += adv ? 1 : 0;
        }
        int j = tt - pre;
        int row = 64 * s + (t >> 2);
        int col = 64 * (s + 1) + 64 * j + (t & 3) * 16;
        float* p = attn + ((size_t)bh * SEQ + row) * SEQ + col;
        __builtin_nontemporal_store(z4, (f32x4*)(p));
        __builtin_nontemporal_store(z4, (f32x4*)(p + 4));
        __builtin_nontemporal_store(z4, (f32x4*)(p + 8));
        __builtin_nontemporal_store(z4, (f32x4*)(p + 12));
    }
}

// ---------------- L1: dentr (heavy, first) || prep || wcombo || zfill[0,768)
// grid 6985: [0,1024) dentr; [1024,5120) prep; [5120,6217) wcombo; [6217,6985) zfill
__global__ __launch_bounds__(256) void fused_prep_kernel(
    const int* __restrict__ item_inputs,
    const int* __restrict__ label_inputs,
    const int* __restrict__ item_ids,
    const float* __restrict__ embeds,
    const float* __restrict__ W_in,
    const float* __restrict__ Wq,
    const float* __restrict__ Wk,
    const float* __restrict__ Wv,
    const float* __restrict__ Wout,
    const float* __restrict__ bv,
    const float* __restrict__ bout,
    const float* __restrict__ rel,
    const float* __restrict__ tsp,
    unsigned short* __restrict__ Abig,   // 16384 x 512 bf16
    unsigned short* __restrict__ qbf,    // 16384 x 256 bf16
    unsigned short* __restrict__ WTin,   // 256 x 512
    unsigned short* __restrict__ WTq,    // 256 x 256
    unsigned short* __restrict__ WTk,    // 256 x 256
    float* __restrict__ Wvw,             // 256 x 8
    float* __restrict__ bvw,             // 8
    float* __restrict__ logits,          // init to bout
    float* __restrict__ dent,            // [32][512] written directly
    float* __restrict__ denr,            // [32][512] written directly
    float* __restrict__ attn)            // zfill target
{
    const int bid = blockIdx.x;
    const int t = threadIdx.x;

    if (bid < 1024) {            // ---- dentr: 16-row strips, heavy first ----
        const int b = bid >> 5;
        const int s16 = 31 - (bid & 31);
        const int q0 = s16 * 16;
        const int row = t >> 4;
        const int lane16 = t & 15;
        const int qrow = q0 + row;
        const size_t base = ((size_t)(b * SEQ) + qrow) * SEQ;
        float dt = 0.f, dr = 0.f;
        for (int k4 = lane16 * 4; k4 <= qrow; k4 += 64) {
            float4 tv4 = *(const float4*)(tsp + base + k4);
            float4 rv4 = *(const float4*)(rel + base + k4);
            const float* tvp = &tv4.x;
            const float* rvp = &rv4.x;
            #pragma unroll
            for (int j = 0; j < 4; j++) {
                const bool va = (k4 + j) <= qrow;
                dt += va ? __expf(__expf(-fabsf(tvp[j]))) : 0.f;
                dr += (va && rvp[j] != 0.f) ? __expf(rvp[j]) : 0.f;
            }
        }
        dt += __shfl_xor(dt, 1); dt += __shfl_xor(dt, 2);
        dt += __shfl_xor(dt, 4); dt += __shfl_xor(dt, 8);
        dr += __shfl_xor(dr, 1); dr += __shfl_xor(dr, 2);
        dr += __shfl_xor(dr, 4); dr += __shfl_xor(dr, 8);
        if (lane16 == 0) {
            dent[b * SEQ + qrow] = dt;
            denr[b * SEQ + qrow] = dr;
        }
    } else if (bid < 5120) {     // ---- prep ----
        int r = (bid - 1024) * 4 + (t >> 6);
        int j = (t & 63) * 4;
        int item = item_inputs[r];
        int lab  = label_inputs[r];
        int qid  = item_ids[r];
        float4 e4 = *(const float4*)(embeds + (size_t)item * EMB + j);
        ushort4 on  = make_ushort4(f2bf(e4.x), f2bf(e4.y), f2bf(e4.z), f2bf(e4.w));
        ushort4 off = make_ushort4(0, 0, 0, 0);
        *(ushort4*)(Abig + (size_t)r * 512 + j)       = lab ? on : off;
        *(ushort4*)(Abig + (size_t)r * 512 + 256 + j) = lab ? off : on;
        float4 q4 = *(const float4*)(embeds + (size_t)qid * EMB + j);
        *(ushort4*)(qbf + (size_t)r * 256 + j) =
            make_ushort4(f2bf(q4.x), f2bf(q4.y), f2bf(q4.z), f2bf(q4.w));
    } else if (bid < 6217) {     // ---- wcombo ----
        int idx = (bid - 5120) * 256 + t;
        if (idx < 131072) {                       // WTin[n][k] = W_in[k][n], K=512
            int n = idx >> 9, k = idx & 511;
            WTin[idx] = f2bf(W_in[(size_t)k * 256 + n]);
        } else if (idx < 196608) {                // WTq
            int i = idx - 131072;
            int n = i >> 8, k = i & 255;
            WTq[i] = f2bf(Wq[(size_t)k * 256 + n]);
        } else if (idx < 262144) {                // WTk
            int i = idx - 196608;
            int n = i >> 8, k = i & 255;
            WTk[i] = f2bf(Wk[(size_t)k * 256 + n]);
        } else if (idx < 264192) {                // Wvw
            int i = idx - 262144;
            int c = i >> 3, h = i & 7;
            float s = 0.f;
            #pragma unroll
            for (int d = 0; d < 32; d++)
                s += Wv[(size_t)c * 256 + h * 32 + d] * Wout[h * 32 + d];
            Wvw[i] = s;
        } else if (idx < 264200) {                // bvw
            int h = idx - 264192;
            float s = 0.f;
            #pragma unroll
            for (int d = 0; d < 32; d++) s += bv[h * 32 + d] * Wout[h * 32 + d];
            bvw[h] = s;
        } else if (idx < 280584) {                // logits init = bout
            logits[idx - 264200] = bout[0];
        }
    } else {                     // ---- zfill idx [0,768) ----
        zfill_work(bid - 6217, t, attn);
    }
}

// ---------------- MFMA GEMM body: C(M x 256) = A(M x KDIM) * BT^T + bias
template<int KDIM, int RELU, int OUTBF>
static __device__ __forceinline__ void gemm_body(
    const unsigned short* __restrict__ A,
    const unsigned short* __restrict__ BT,
    const float* __restrict__ bias,
    void* __restrict__ Cout, float scale)
{
    __shared__ unsigned short As[64][40];
    __shared__ unsigned short Bs[128][40];
    const int t = threadIdx.x;
    const int row0 = blockIdx.x * 64;
    const int col0 = blockIdx.y * 128;
    const int wid = t >> 6, lane = t & 63;
    const int wm = wid & 1, wn = wid >> 1;
    const int lg = lane >> 4, l15 = lane & 15;

    f32x4 acc[2][4];
    #pragma unroll
    for (int i = 0; i < 2; i++)
        #pragma unroll
        for (int j = 0; j < 4; j++) acc[i][j] = (f32x4){0.f, 0.f, 0.f, 0.f};

    const int arow = t >> 2, achk = t & 3;
    const int brow = t >> 1, bhalf = t & 1;

    for (int k0 = 0; k0 < KDIM; k0 += 32) {
        __syncthreads();
        *(uint4*)(&As[arow][achk * 8]) =
            *(const uint4*)(A + (size_t)(row0 + arow) * KDIM + k0 + achk * 8);
        const unsigned short* bsrc = BT + (size_t)(col0 + brow) * KDIM + k0 + bhalf * 16;
        *(uint4*)(&Bs[brow][bhalf * 16])     = *(const uint4*)(bsrc);
        *(uint4*)(&Bs[brow][bhalf * 16 + 8]) = *(const uint4*)(bsrc + 8);
        __syncthreads();
        bf16x8 af[2], bfr[4];
        #pragma unroll
        for (int fm = 0; fm < 2; fm++)
            af[fm] = *(const bf16x8*)(&As[wm * 32 + fm * 16 + l15][lg * 8]);
        #pragma unroll
        for (int fn = 0; fn < 4; fn++)
            bfr[fn] = *(const bf16x8*)(&Bs[wn * 64 + fn * 16 + l15][lg * 8]);
        #pragma unroll
        for (int fm = 0; fm < 2; fm++)
            #pragma unroll
            for (int fn = 0; fn < 4; fn++)
                acc[fm][fn] = __builtin_amdgcn_mfma_f32_16x16x32_bf16(
                    af[fm], bfr[fn], acc[fm][fn], 0, 0, 0);
    }
    #pragma unroll
    for (int fm = 0; fm < 2; fm++)
        #pragma unroll
        for (int fn = 0; fn < 4; fn++) {
            int col = col0 + wn * 64 + fn * 16 + l15;
            float bvv = bias[col];
            #pragma unroll
            for (int r = 0; r < 4; r++) {
                int row = row0 + wm * 32 + fm * 16 + lg * 4 + r;
                float v = acc[fm][fn][r] + bvv;
                if (RELU) v = fmaxf(v, 0.f);
                v *= scale;
                if (OUTBF) ((unsigned short*)Cout)[(size_t)row * 256 + col] = f2bf(v);
                else       ((float*)Cout)[(size_t)row * 256 + col] = v;
            }
        }
}

// ---------------- L2: X-GEMM || Q-GEMM || zfill[768,1280) via z
__global__ __launch_bounds__(256, 2) void gemmA_kernel(
    const unsigned short* __restrict__ Abig,
    const unsigned short* __restrict__ WTin,
    const float* __restrict__ b_in,
    unsigned short* __restrict__ Xbf,
    const unsigned short* __restrict__ qbf,
    const unsigned short* __restrict__ WTq,
    const float* __restrict__ bq,
    unsigned short* __restrict__ Qbf,
    float* __restrict__ attn)
{
    if (blockIdx.z == 0)
        gemm_body<512, 1, 1>(Abig, WTin, b_in, (void*)Xbf, 1.0f);
    else if (blockIdx.z == 1)
        gemm_body<256, 0, 1>(qbf, WTq, bq, (void*)Qbf, 0.17677669529663687f);
    else
        zfill_work(768 + (blockIdx.y << 8) + blockIdx.x, threadIdx.x, attn);
}

// ---------------- Vw body: Vw[row][h] = X[row]·Wvw[:,h] + bvw[h]
static __device__ __forceinline__ void vw_body(
    const unsigned short* __restrict__ Xbf,
    const float* __restrict__ Wvw,
    const float* __restrict__ bvw,
    float* __restrict__ Vw)
{
    __shared__ float sW[2048];
    __shared__ float sb[8];
    int t = threadIdx.x;
    #pragma unroll
    for (int i = 0; i < 8; i++) sW[i * 256 + t] = Wvw[i * 256 + t];
    if (t < 8) sb[t] = bvw[t];
    __syncthreads();
    int row = blockIdx.x * 256 + t;
    float acc[8];
    #pragma unroll
    for (int h = 0; h < 8; h++) acc[h] = sb[h];
    for (int d0 = 0; d0 < 32; d0++) {
        bf16x8 x = *(const bf16x8*)(Xbf + (size_t)row * 256 + d0 * 8);
        #pragma unroll
        for (int j = 0; j < 8; j++) {
            float xf = bf2f((unsigned short)x[j]);
            #pragma unroll
            for (int h = 0; h < 8; h++) acc[h] += xf * sW[(d0 * 8 + j) * 8 + h];
        }
    }
    *(float4*)(Vw + (size_t)row * 8)     = make_float4(acc[0], acc[1], acc[2], acc[3]);
    *(float4*)(Vw + (size_t)row * 8 + 4) = make_float4(acc[4], acc[5], acc[6], acc[7]);
}

// ---------------- L3: K-GEMM || Vw || zfill[1280,1792) via z
__global__ __launch_bounds__(256, 2) void gemmB_kernel(
    const unsigned short* __restrict__ Xbf,
    const unsigned short* __restrict__ WTk,
    const float* __restrict__ bk,
    unsigned short* __restrict__ Kbf,
    const float* __restrict__ Wvw,
    const float* __restrict__ bvw,
    float* __restrict__ Vw,
    float* __restrict__ attn)
{
    if (blockIdx.z == 0) {
        gemm_body<256, 0, 1>(Xbf, WTk, bk, (void*)Kbf, 1.0f);
    } else if (blockIdx.z == 1) {
        if (blockIdx.x >= 64 || blockIdx.y != 0) return;
        vw_body(Xbf, Wvw, bvw, Vw);
    } else {
        zfill_work(1280 + (blockIdx.y << 8) + blockIdx.x, threadIdx.x, attn);
    }
}

// ---------------- L4: attnW v7 — fused flash; writes ONLY valid-prefix groups
// grid 8192: id -> strip heavy-first (32) x b (32) x h (8); 256 threads = 4 waves
__global__ __launch_bounds__(256, 8) void attnW_kernel(
    const unsigned short* __restrict__ Qbf,
    const unsigned short* __restrict__ Kbf,
    const float* __restrict__ Vw,
    const float* __restrict__ rel,
    const float* __restrict__ tsp,
    const float* __restrict__ dent,
    const float* __restrict__ denr,
    const float* __restrict__ pl1,
    const float* __restrict__ pl2,
    float* __restrict__ logits,
    float* __restrict__ attn)
{
    __shared__ unsigned short sP[16][520];  // exp(score) bf16
    __shared__ float sVw[512];
    __shared__ float sden[4][16];

    const int t = threadIdx.x;
    const int id = blockIdx.x;
    const int qt16 = 31 - (id >> 8);      // heavy strips dispatched first
    const int b = (id >> 3) & 31;
    const int h = id & 7;
    const int q0 = qt16 * 16;
    const int qmax = q0 + 15;

    const int w = t >> 6, lane = t & 63;
    const int l15 = lane & 15, lg = lane >> 4;

    const float l1 = pl1[0], l2 = pl2[0];
    const float cp = (1.f - l1) * (1.f - l2);
    const float ct = (1.f - l1) * l2;
    const float cr = l1;

    // stage Vw column h for this b
    sVw[t]       = Vw[((size_t)(b * SEQ) + t) * 8 + h];
    sVw[256 + t] = Vw[((size_t)(b * SEQ) + 256 + t) * 8 + h];

    // Q fragment: rows q0+l15, dims h*32 + lg*8
    bf16x8 aq = *(const bf16x8*)(Qbf + (size_t)(b * SEQ + q0 + l15) * EMB + h * 32 + lg * 8);

    // ---- phase 1: MFMA scores -> exp -> sP (bf16); per-row den partials in f32 ----
    float dp[4] = {0.f, 0.f, 0.f, 0.f};
    #pragma unroll
    for (int ki = 0; ki < 4; ki++) {
        const int kt = w + ki * 4;        // wave-uniform tile index 0..15
        const int k0 = kt * 32;
        if (k0 <= qmax) {
            #pragma unroll
            for (int nf = 0; nf < 2; nf++) {
                const int kcol = k0 + nf * 16 + l15;
                bf16x8 bk = *(const bf16x8*)(Kbf +
                    (size_t)(b * SEQ + kcol) * EMB + h * 32 + lg * 8);
                f32x4 am = __builtin_amdgcn_mfma_f32_16x16x32_bf16(
                    aq, bk, (f32x4){0.f, 0.f, 0.f, 0.f}, 0, 0, 0);
                #pragma unroll
                for (int r = 0; r < 4; r++) {
                    const int qloc = lg * 4 + r;
                    float e = (kcol <= q0 + qloc) ? __expf(am[r]) : 0.f;
                    sP[qloc][kcol] = f2bf(e);
                    dp[r] += e;
                }
            }
        } else if (k0 <= qmax + 64) {
            // only the group straddling the strip needs LDS zeros; deeper groups unwritten
            #pragma unroll
            for (int nf = 0; nf < 2; nf++)
                #pragma unroll
                for (int r = 0; r < 4; r++)
                    sP[lg * 4 + r][k0 + nf * 16 + l15] = 0;
        }
    }
    #pragma unroll
    for (int r = 0; r < 4; r++) {
        float v = dp[r];
        v += __shfl_xor(v, 1); v += __shfl_xor(v, 2);
        v += __shfl_xor(v, 4); v += __shfl_xor(v, 8);
        if (l15 == 0) sden[w][lg * 4 + r] = v;
    }
    __syncthreads();

    // ---- phase 2: normalize + blend + nt write (valid-prefix groups only) ----
    const int wrow = t >> 4;
    const int wcol = (t & 15) * 4;
    const int qrow_w = q0 + wrow;
    const int smax = qrow_w >> 6;         // last 64-col group with start <= qrow
    const float den = sden[0][wrow] + sden[1][wrow] + sden[2][wrow] + sden[3][wrow];
    const float cpinv = cp / den;
    const float dtv = dent[b * SEQ + qrow_w];
    const float drv = denr[b * SEQ + qrow_w];
    const float ctt = ct / dtv;
    const float crr = drv > 0.f ? cr / drv : 0.f;

    float* arow = attn + ((size_t)((b * NHEAD + h) * SEQ) + qrow_w) * SEQ;
    const size_t rbase = ((size_t)(b * SEQ) + qrow_w) * SEQ;
    const f32x4 z4 = (f32x4){0.f, 0.f, 0.f, 0.f};
    float plog = 0.f;

    for (int s = 0; s <= smax; s++) {
        const int c = wcol + s * 64;
        f32x4 o;
        if (c > qrow_w) {
            o = z4;                       // lanes past diagonal within diagonal group
        } else {
            float4 tv4 = *(const float4*)(tsp + rbase + c);
            float4 rv4 = *(const float4*)(rel + rbase + c);
            ushort4 p4 = *(const ushort4*)(&sP[wrow][c]);
            const float* tvp = &tv4.x;
            const float* rvp = &rv4.x;
            const unsigned short* pp = &p4.x;
            #pragma unroll
            for (int j = 0; j < 4; j++) {
                const bool va = (c + j) <= qrow_w;
                float e_t = va ? __expf(__expf(-fabsf(tvp[j]))) * ctt : 0.f;
                float e_r = (va && rvp[j] != 0.f) ? __expf(rvp[j]) * crr : 0.f;
                float a = fmaf(bf2f(pp[j]), cpinv, e_t + e_r);
                a = va ? a : 0.f;
                o[j] = a;
                plog = fmaf(a, sVw[c + j], plog);
            }
        }
        __builtin_nontemporal_store(o, (f32x4*)(arow + c));
    }

    // per-row logits: reduce over the 16 col-lanes, one atomic per row
    plog += __shfl_xor(plog, 1); plog += __shfl_xor(plog, 2);
    plog += __shfl_xor(plog, 4); plog += __shfl_xor(plog, 8);
    if ((t & 15) == 0)
        atomicAdd(&logits[b * SEQ + qrow_w], plog);
}

// ---------------- host launch ----------------
extern "C" void kernel_launch(void* const* d_in, const int* in_sizes, int n_in,
                              void* d_out, int out_size, void* d_ws, size_t ws_size,
                              hipStream_t stream)
{
    (void)in_sizes; (void)n_in; (void)out_size; (void)ws_size;
    const int*   item_inputs  = (const int*)d_in[0];
    const int*   label_inputs = (const int*)d_in[1];
    const int*   item_ids     = (const int*)d_in[2];
    const float* rel   = (const float*)d_in[3];
    const float* tsp   = (const float*)d_in[4];
    const float* emb   = (const float*)d_in[5];
    const float* W_in  = (const float*)d_in[6];
    const float* b_in  = (const float*)d_in[7];
    const float* Wq    = (const float*)d_in[8];
    const float* bq    = (const float*)d_in[9];
    const float* Wk    = (const float*)d_in[10];
    const float* bk    = (const float*)d_in[11];
    const float* Wv    = (const float*)d_in[12];
    const float* bv    = (const float*)d_in[13];
    const float* Wout  = (const float*)d_in[14];
    const float* bout  = (const float*)d_in[15];
    const float* l1    = (const float*)d_in[16];
    const float* l2    = (const float*)d_in[17];

    const size_t R = 16384;
    char* w = (char*)d_ws;
    unsigned short* Abig = (unsigned short*)w; w += R * 512 * 2;
    unsigned short* qbf  = (unsigned short*)w; w += R * 256 * 2;
    unsigned short* WTin = (unsigned short*)w; w += (size_t)256 * 512 * 2;
    unsigned short* WTq  = (unsigned short*)w; w += (size_t)256 * 256 * 2;
    unsigned short* WTk  = (unsigned short*)w; w += (size_t)256 * 256 * 2;
    unsigned short* Xbf  = (unsigned short*)w; w += R * 256 * 2;
    unsigned short* Qbf  = (unsigned short*)w; w += R * 256 * 2;
    unsigned short* Kbf  = (unsigned short*)w; w += R * 256 * 2;
    float* Wvw  = (float*)w; w += 2048 * 4;
    float* Vw   = (float*)w; w += R * 8 * 4;
    float* bvw  = (float*)w; w += 256;          // 8 floats + pad
    float* dent = (float*)w; w += (size_t)32 * SEQ * 4;           // 64 KB
    float* denr = (float*)w; w += (size_t)32 * SEQ * 4;           // 64 KB

    float* logits = (float*)d_out;
    float* attnp  = (float*)d_out + 16384;

    // L1: dentr (first, heavy) || prep || wcombo (+logits init) || zfill part 1
    fused_prep_kernel<<<dim3(6985), dim3(256), 0, stream>>>(
        item_inputs, label_inputs, item_ids, emb,
        W_in, Wq, Wk, Wv, Wout, bv, bout, rel, tsp,
        Abig, qbf, WTin, WTq, WTk, Wvw, bvw, logits, dent, denr, attnp);

    // L2: X-GEMM || Q-GEMM || zfill part 2
    gemmA_kernel<<<dim3(256, 2, 3), dim3(256), 0, stream>>>(
        Abig, WTin, b_in, Xbf, qbf, WTq, bq, Qbf, attnp);

    // L3: K-GEMM || Vw || zfill part 3
    gemmB_kernel<<<dim3(256, 2, 3), dim3(256), 0, stream>>>(
        Xbf, WTk, bk, Kbf, Wvw, bvw, Vw, attnp);

    // L4: fused attention — valid-prefix writes only
    attnW_kernel<<<dim3(8192), dim3(256), 0, stream>>>(
        Qbf, Kbf, Vw, rel, tsp, dent, denr, l1, l2, logits, attnp);
}

// Round 15
// 150.205 us; speedup vs baseline: 1.5122x; 1.5122x over previous
//
#include <hip/hip_runtime.h>
#include <hip/hip_bf16.h>

#define SEQ 512
#define EMB 256
#define NHEAD 8
#define HD 32

using bf16x8 = __attribute__((ext_vector_type(8))) short;
using f32x4  = __attribute__((ext_vector_type(4))) float;

static __device__ __forceinline__ unsigned short f2bf(float x) {
    union { float f; unsigned int u; } v; v.f = x;
    unsigned int r = v.u + 0x7FFFu + ((v.u >> 16) & 1u);
    return (unsigned short)(r >> 16);
}
static __device__ __forceinline__ float bf2f(unsigned short v) {
    union { unsigned int u; float f; } w; w.u = ((unsigned int)v) << 16; return w.f;
}

// ---------------- L1: prep (gather+concat) || wcombo (weights+init)
// grid 5193: [0,4096) prep; [4096,5193) wcombo
__global__ __launch_bounds__(256) void fused_prep_kernel(
    const int* __restrict__ item_inputs,
    const int* __restrict__ label_inputs,
    const int* __restrict__ item_ids,
    const float* __restrict__ embeds,
    const float* __restrict__ W_in,
    const float* __restrict__ Wq,
    const float* __restrict__ Wk,
    const float* __restrict__ Wv,
    const float* __restrict__ Wout,
    const float* __restrict__ bv,
    const float* __restrict__ bout,
    unsigned short* __restrict__ Abig,   // 16384 x 512 bf16
    unsigned short* __restrict__ qbf,    // 16384 x 256 bf16
    unsigned short* __restrict__ WTin,   // 256 x 512
    unsigned short* __restrict__ WTq,    // 256 x 256
    unsigned short* __restrict__ WTk,    // 256 x 256
    float* __restrict__ Wvw,             // 256 x 8
    float* __restrict__ bvw,             // 8
    float* __restrict__ logits)          // init to bout (overwritten by attnF)
{
    const int bid = blockIdx.x;
    const int t = threadIdx.x;

    if (bid < 4096) {            // ---- prep ----
        int r = bid * 4 + (t >> 6);
        int j = (t & 63) * 4;
        int item = item_inputs[r];
        int lab  = label_inputs[r];
        int qid  = item_ids[r];
        float4 e4 = *(const float4*)(embeds + (size_t)item * EMB + j);
        ushort4 on  = make_ushort4(f2bf(e4.x), f2bf(e4.y), f2bf(e4.z), f2bf(e4.w));
        ushort4 off = make_ushort4(0, 0, 0, 0);
        *(ushort4*)(Abig + (size_t)r * 512 + j)       = lab ? on : off;
        *(ushort4*)(Abig + (size_t)r * 512 + 256 + j) = lab ? off : on;
        float4 q4 = *(const float4*)(embeds + (size_t)qid * EMB + j);
        *(ushort4*)(qbf + (size_t)r * 256 + j) =
            make_ushort4(f2bf(q4.x), f2bf(q4.y), f2bf(q4.z), f2bf(q4.w));
    } else {                     // ---- wcombo ----
        int idx = (bid - 4096) * 256 + t;
        if (idx < 131072) {                       // WTin[n][k] = W_in[k][n], K=512
            int n = idx >> 9, k = idx & 511;
            WTin[idx] = f2bf(W_in[(size_t)k * 256 + n]);
        } else if (idx < 196608) {                // WTq
            int i = idx - 131072;
            int n = i >> 8, k = i & 255;
            WTq[i] = f2bf(Wq[(size_t)k * 256 + n]);
        } else if (idx < 262144) {                // WTk
            int i = idx - 196608;
            int n = i >> 8, k = i & 255;
            WTk[i] = f2bf(Wk[(size_t)k * 256 + n]);
        } else if (idx < 264192) {                // Wvw
            int i = idx - 262144;
            int c = i >> 3, h = i & 7;
            float s = 0.f;
            #pragma unroll
            for (int d = 0; d < 32; d++)
                s += Wv[(size_t)c * 256 + h * 32 + d] * Wout[h * 32 + d];
            Wvw[i] = s;
        } else if (idx < 264200) {                // bvw
            int h = idx - 264192;
            float s = 0.f;
            #pragma unroll
            for (int d = 0; d < 32; d++) s += bv[h * 32 + d] * Wout[h * 32 + d];
            bvw[h] = s;
        } else if (idx < 280584) {                // logits init = bout
            logits[idx - 264200] = bout[0];
        }
    }
}

// ---------------- MFMA GEMM body: C(M x 256) = A(M x KDIM) * BT^T + bias
template<int KDIM, int RELU, int OUTBF>
static __device__ __forceinline__ void gemm_body(
    const unsigned short* __restrict__ A,
    const unsigned short* __restrict__ BT,
    const float* __restrict__ bias,
    void* __restrict__ Cout, float scale)
{
    __shared__ unsigned short As[64][40];
    __shared__ unsigned short Bs[128][40];
    const int t = threadIdx.x;
    const int row0 = blockIdx.x * 64;
    const int col0 = blockIdx.y * 128;
    const int wid = t >> 6, lane = t & 63;
    const int wm = wid & 1, wn = wid >> 1;
    const int lg = lane >> 4, l15 = lane & 15;

    f32x4 acc[2][4];
    #pragma unroll
    for (int i = 0; i < 2; i++)
        #pragma unroll
        for (int j = 0; j < 4; j++) acc[i][j] = (f32x4){0.f, 0.f, 0.f, 0.f};

    const int arow = t >> 2, achk = t & 3;
    const int brow = t >> 1, bhalf = t & 1;

    for (int k0 = 0; k0 < KDIM; k0 += 32) {
        __syncthreads();
        *(uint4*)(&As[arow][achk * 8]) =
            *(const uint4*)(A + (size_t)(row0 + arow) * KDIM + k0 + achk * 8);
        const unsigned short* bsrc = BT + (size_t)(col0 + brow) * KDIM + k0 + bhalf * 16;
        *(uint4*)(&Bs[brow][bhalf * 16])     = *(const uint4*)(bsrc);
        *(uint4*)(&Bs[brow][bhalf * 16 + 8]) = *(const uint4*)(bsrc + 8);
        __syncthreads();
        bf16x8 af[2], bfr[4];
        #pragma unroll
        for (int fm = 0; fm < 2; fm++)
            af[fm] = *(const bf16x8*)(&As[wm * 32 + fm * 16 + l15][lg * 8]);
        #pragma unroll
        for (int fn = 0; fn < 4; fn++)
            bfr[fn] = *(const bf16x8*)(&Bs[wn * 64 + fn * 16 + l15][lg * 8]);
        #pragma unroll
        for (int fm = 0; fm < 2; fm++)
            #pragma unroll
            for (int fn = 0; fn < 4; fn++)
                acc[fm][fn] = __builtin_amdgcn_mfma_f32_16x16x32_bf16(
                    af[fm], bfr[fn], acc[fm][fn], 0, 0, 0);
    }
    #pragma unroll
    for (int fm = 0; fm < 2; fm++)
        #pragma unroll
        for (int fn = 0; fn < 4; fn++) {
            int col = col0 + wn * 64 + fn * 16 + l15;
            float bvv = bias[col];
            #pragma unroll
            for (int r = 0; r < 4; r++) {
                int row = row0 + wm * 32 + fm * 16 + lg * 4 + r;
                float v = acc[fm][fn][r] + bvv;
                if (RELU) v = fmaxf(v, 0.f);
                v *= scale;
                if (OUTBF) ((unsigned short*)Cout)[(size_t)row * 256 + col] = f2bf(v);
                else       ((float*)Cout)[(size_t)row * 256 + col] = v;
            }
        }
}

// ---------------- L2: X-GEMM (K=512, relu) || Q-GEMM via z
__global__ __launch_bounds__(256, 2) void gemmA_kernel(
    const unsigned short* __restrict__ Abig,
    const unsigned short* __restrict__ WTin,
    const float* __restrict__ b_in,
    unsigned short* __restrict__ Xbf,
    const unsigned short* __restrict__ qbf,
    const unsigned short* __restrict__ WTq,
    const float* __restrict__ bq,
    unsigned short* __restrict__ Qbf)
{
    if (blockIdx.z == 0)
        gemm_body<512, 1, 1>(Abig, WTin, b_in, (void*)Xbf, 1.0f);
    else
        gemm_body<256, 0, 1>(qbf, WTq, bq, (void*)Qbf, 0.17677669529663687f);
}

// ---------------- Vw body: VwT[b][h][row] = X[row]·Wvw[:,h] + bvw[h]
static __device__ __forceinline__ void vw_body(
    const unsigned short* __restrict__ Xbf,
    const float* __restrict__ Wvw,
    const float* __restrict__ bvw,
    float* __restrict__ VwT)
{
    __shared__ float sW[2048];
    __shared__ float sb[8];
    int t = threadIdx.x;
    #pragma unroll
    for (int i = 0; i < 8; i++) sW[i * 256 + t] = Wvw[i * 256 + t];
    if (t < 8) sb[t] = bvw[t];
    __syncthreads();
    int row = blockIdx.x * 256 + t;
    float acc[8];
    #pragma unroll
    for (int h = 0; h < 8; h++) acc[h] = sb[h];
    for (int d0 = 0; d0 < 32; d0++) {
        bf16x8 x = *(const bf16x8*)(Xbf + (size_t)row * 256 + d0 * 8);
        #pragma unroll
        for (int j = 0; j < 8; j++) {
            float xf = bf2f((unsigned short)x[j]);
            #pragma unroll
            for (int h = 0; h < 8; h++) acc[h] += xf * sW[(d0 * 8 + j) * 8 + h];
        }
    }
    const int bb = row >> 9, rr = row & 511;
    #pragma unroll
    for (int h = 0; h < 8; h++)
        VwT[((size_t)(bb * NHEAD + h)) * SEQ + rr] = acc[h];   // coalesced per h
}

// ---------------- L3: K-GEMM || VwT via z
__global__ __launch_bounds__(256, 2) void gemmB_kernel(
    const unsigned short* __restrict__ Xbf,
    const unsigned short* __restrict__ WTk,
    const float* __restrict__ bk,
    unsigned short* __restrict__ Kbf,
    const float* __restrict__ Wvw,
    const float* __restrict__ bvw,
    float* __restrict__ VwT)
{
    if (blockIdx.z == 0) {
        gemm_body<256, 0, 1>(Xbf, WTk, bk, (void*)Kbf, 1.0f);
    } else {
        if (blockIdx.x >= 64 || blockIdx.y != 0) return;
        vw_body(Xbf, Wvw, bvw, VwT);
    }
}

// ---------------- L4: attnF — block = (b, 16-row strip), ALL 8 heads.
// Phase A: rel/ts read ONCE -> numerators (bf16 pair, LDS) + row sums.
// Phase B x8: MFMA scores -> sP -> normalize+blend+nt write+logits.
// grid 1024: id -> b (32, outer: K reuse in L2) x strip (32, heavy-first)
__global__ __launch_bounds__(256, 3) void attnF_kernel(
    const unsigned short* __restrict__ Qbf,
    const unsigned short* __restrict__ Kbf,
    const float* __restrict__ VwT,
    const float* __restrict__ rel,
    const float* __restrict__ tsp,
    const float* __restrict__ bout,
    const float* __restrict__ pl1,
    const float* __restrict__ pl2,
    float* __restrict__ logits,
    float* __restrict__ attn)
{
    __shared__ unsigned int   sNum[16][520];  // (et_bf16) | (er_bf16 << 16)
    __shared__ unsigned short sP[16][520];    // exp(score) bf16, per head
    __shared__ float sden[4][16];
    __shared__ float sctt[16], scrr[16];

    const int t = threadIdx.x;
    const int id = blockIdx.x;
    const int b = id >> 5;
    const int qt16 = 31 - (id & 31);      // heavy strips first within each b
    const int q0 = qt16 * 16;
    const int qmax = q0 + 15;

    const int w = t >> 6, lane = t & 63;
    const int l15 = lane & 15, lg = lane >> 4;

    const float l1 = pl1[0], l2 = pl2[0];
    const float cp = (1.f - l1) * (1.f - l2);
    const float ct = (1.f - l1) * l2;
    const float cr = l1;

    // row geometry (phase A and write pass)
    const int wrow = t >> 4;              // 0..15
    const int lane16 = t & 15;
    const int qrow_w = q0 + wrow;
    const size_t rbase = ((size_t)(b * SEQ) + qrow_w) * SEQ;

    // ---- phase A: numerators + row sums (rel/ts read once for all heads) ----
    float dt = 0.f, dr = 0.f;
    for (int k4 = lane16 * 4; k4 <= qrow_w; k4 += 64) {
        float4 tv4 = *(const float4*)(tsp + rbase + k4);
        float4 rv4 = *(const float4*)(rel + rbase + k4);
        const float* tvp = &tv4.x;
        const float* rvp = &rv4.x;
        unsigned int pk[4];
        #pragma unroll
        for (int j = 0; j < 4; j++) {
            const bool va = (k4 + j) <= qrow_w;
            float et = va ? __expf(__expf(-fabsf(tvp[j]))) : 0.f;
            float er = (va && rvp[j] != 0.f) ? __expf(rvp[j]) : 0.f;
            dt += et; dr += er;
            pk[j] = (unsigned int)f2bf(et) | ((unsigned int)f2bf(er) << 16);
        }
        *(uint4*)(&sNum[wrow][k4]) = make_uint4(pk[0], pk[1], pk[2], pk[3]);
    }
    dt += __shfl_xor(dt, 1); dt += __shfl_xor(dt, 2);
    dt += __shfl_xor(dt, 4); dt += __shfl_xor(dt, 8);
    dr += __shfl_xor(dr, 1); dr += __shfl_xor(dr, 2);
    dr += __shfl_xor(dr, 4); dr += __shfl_xor(dr, 8);
    if (lane16 == 0) {
        sctt[wrow] = ct / dt;
        scrr[wrow] = dr > 0.f ? cr / dr : 0.f;
    }

    const f32x4 z4 = (f32x4){0.f, 0.f, 0.f, 0.f};
    float plog = 0.f;

    // ---- phase B: per head ----
    #pragma unroll 1
    for (int h = 0; h < 8; h++) {
        // scores (wave geometry): wave w owns kt = w, w+4, w+8, w+12
        bf16x8 aq = *(const bf16x8*)(Qbf +
            (size_t)(b * SEQ + q0 + l15) * EMB + h * 32 + lg * 8);
        float dp[4] = {0.f, 0.f, 0.f, 0.f};
        #pragma unroll
        for (int ki = 0; ki < 4; ki++) {
            const int k0 = (w + ki * 4) * 32;
            if (k0 <= qmax) {
                #pragma unroll
                for (int nf = 0; nf < 2; nf++) {
                    const int kcol = k0 + nf * 16 + l15;
                    bf16x8 bk = *(const bf16x8*)(Kbf +
                        (size_t)(b * SEQ + kcol) * EMB + h * 32 + lg * 8);
                    f32x4 am = __builtin_amdgcn_mfma_f32_16x16x32_bf16(
                        aq, bk, (f32x4){0.f, 0.f, 0.f, 0.f}, 0, 0, 0);
                    #pragma unroll
                    for (int r = 0; r < 4; r++) {
                        const int qloc = lg * 4 + r;
                        float e = (kcol <= q0 + qloc) ? __expf(am[r]) : 0.f;
                        sP[qloc][kcol] = f2bf(e);
                        dp[r] += e;
                    }
                }
            }
        }
        #pragma unroll
        for (int r = 0; r < 4; r++) {
            float v = dp[r];
            v += __shfl_xor(v, 1); v += __shfl_xor(v, 2);
            v += __shfl_xor(v, 4); v += __shfl_xor(v, 8);
            if (l15 == 0) sden[w][lg * 4 + r] = v;
        }
        __syncthreads();

        // write pass (row geometry)
        const float den = sden[0][wrow] + sden[1][wrow] + sden[2][wrow] + sden[3][wrow];
        const float cpinv = cp / den;
        const float ctt = sctt[wrow];
        const float crr = scrr[wrow];
        float* arow = attn + ((size_t)((b * NHEAD + h) * SEQ) + qrow_w) * SEQ;
        const float* vwh = VwT + ((size_t)(b * NHEAD + h)) * SEQ;

        #pragma unroll
        for (int s = 0; s < 8; s++) {
            const int c = lane16 * 4 + s * 64;
            f32x4 o;
            if (c > qrow_w) {
                o = z4;
            } else {
                uint4   nv = *(const uint4*)(&sNum[wrow][c]);
                ushort4 p4 = *(const ushort4*)(&sP[wrow][c]);
                float4  v4 = *(const float4*)(vwh + c);
                const unsigned int* np = &nv.x;
                const unsigned short* pp = &p4.x;
                const float* vp = &v4.x;
                #pragma unroll
                for (int j = 0; j < 4; j++) {
                    const bool va = (c + j) <= qrow_w;
                    float et = bf2f((unsigned short)(np[j] & 0xffffu));
                    float er = bf2f((unsigned short)(np[j] >> 16));
                    float a = fmaf(bf2f(pp[j]), cpinv, fmaf(et, ctt, er * crr));
                    a = va ? a : 0.f;
                    o[j] = a;
                    plog = fmaf(a, vp[j], plog);
                }
            }
            __builtin_nontemporal_store(o, (f32x4*)(arow + c));
        }
        __syncthreads();   // protect sP/sden before next head
    }

    // logits: each (b,qrow) owned by exactly this block -> plain store
    plog += __shfl_xor(plog, 1); plog += __shfl_xor(plog, 2);
    plog += __shfl_xor(plog, 4); plog += __shfl_xor(plog, 8);
    if (lane16 == 0)
        logits[b * SEQ + qrow_w] = bout[0] + plog;
}

// ---------------- host launch ----------------
extern "C" void kernel_launch(void* const* d_in, const int* in_sizes, int n_in,
                              void* d_out, int out_size, void* d_ws, size_t ws_size,
                              hipStream_t stream)
{
    (void)in_sizes; (void)n_in; (void)out_size; (void)ws_size;
    const int*   item_inputs  = (const int*)d_in[0];
    const int*   label_inputs = (const int*)d_in[1];
    const int*   item_ids     = (const int*)d_in[2];
    const float* rel   = (const float*)d_in[3];
    const float* tsp   = (const float*)d_in[4];
    const float* emb   = (const float*)d_in[5];
    const float* W_in  = (const float*)d_in[6];
    const float* b_in  = (const float*)d_in[7];
    const float* Wq    = (const float*)d_in[8];
    const float* bq    = (const float*)d_in[9];
    const float* Wk    = (const float*)d_in[10];
    const float* bk    = (const float*)d_in[11];
    const float* Wv    = (const float*)d_in[12];
    const float* bv    = (const float*)d_in[13];
    const float* Wout  = (const float*)d_in[14];
    const float* bout  = (const float*)d_in[15];
    const float* l1    = (const float*)d_in[16];
    const float* l2    = (const float*)d_in[17];

    const size_t R = 16384;
    char* w = (char*)d_ws;
    unsigned short* Abig = (unsigned short*)w; w += R * 512 * 2;
    unsigned short* qbf  = (unsigned short*)w; w += R * 256 * 2;
    unsigned short* WTin = (unsigned short*)w; w += (size_t)256 * 512 * 2;
    unsigned short* WTq  = (unsigned short*)w; w += (size_t)256 * 256 * 2;
    unsigned short* WTk  = (unsigned short*)w; w += (size_t)256 * 256 * 2;
    unsigned short* Xbf  = (unsigned short*)w; w += R * 256 * 2;
    unsigned short* Qbf  = (unsigned short*)w; w += R * 256 * 2;
    unsigned short* Kbf  = (unsigned short*)w; w += R * 256 * 2;
    float* Wvw  = (float*)w; w += 2048 * 4;
    float* VwT  = (float*)w; w += R * 8 * 4;    // [32][8][512]
    float* bvw  = (float*)w; w += 256;          // 8 floats + pad

    float* logits = (float*)d_out;
    float* attnp  = (float*)d_out + 16384;

    // L1: prep || wcombo (+logits init)
    fused_prep_kernel<<<dim3(5193), dim3(256), 0, stream>>>(
        item_inputs, label_inputs, item_ids, emb,
        W_in, Wq, Wk, Wv, Wout, bv, bout,
        Abig, qbf, WTin, WTq, WTk, Wvw, bvw, logits);

    // L2: X-GEMM || Q-GEMM
    gemmA_kernel<<<dim3(256, 2, 2), dim3(256), 0, stream>>>(
        Abig, WTin, b_in, Xbf, qbf, WTq, bq, Qbf);

    // L3: K-GEMM || VwT
    gemmB_kernel<<<dim3(256, 2, 2), dim3(256), 0, stream>>>(
        Xbf, WTk, bk, Kbf, Wvw, bvw, VwT);

    // L4: fused attention, all heads per block, rel/ts read once
    attnF_kernel<<<dim3(1024), dim3(256), 0, stream>>>(
        Qbf, Kbf, VwT, rel, tsp, bout, l1, l2, logits, attnp);
}

// Round 16
// 145.567 us; speedup vs baseline: 1.5604x; 1.0319x over previous
//
#include <hip/hip_runtime.h>
#include <hip/hip_bf16.h>

#define SEQ 512
#define EMB 256
#define NHEAD 8
#define HD 32

using bf16x8 = __attribute__((ext_vector_type(8))) short;
using f32x4  = __attribute__((ext_vector_type(4))) float;

static __device__ __forceinline__ unsigned short f2bf(float x) {
    union { float f; unsigned int u; } v; v.f = x;
    unsigned int r = v.u + 0x7FFFu + ((v.u >> 16) & 1u);
    return (unsigned short)(r >> 16);
}
static __device__ __forceinline__ float bf2f(unsigned short v) {
    union { unsigned int u; float f; } w; w.u = ((unsigned int)v) << 16; return w.f;
}

// ---------------- L1: dentr (heavy, first) || prep || wcombo
// grid 6217: [0,1024) dentr; [1024,5120) prep; [5120,6217) wcombo
__global__ __launch_bounds__(256) void fused_prep_kernel(
    const int* __restrict__ item_inputs,
    const int* __restrict__ label_inputs,
    const int* __restrict__ item_ids,
    const float* __restrict__ embeds,
    const float* __restrict__ W_in,
    const float* __restrict__ Wq,
    const float* __restrict__ Wk,
    const float* __restrict__ Wv,
    const float* __restrict__ Wout,
    const float* __restrict__ bv,
    const float* __restrict__ bout,
    const float* __restrict__ rel,
    const float* __restrict__ tsp,
    unsigned short* __restrict__ Abig,   // 16384 x 512 bf16
    unsigned short* __restrict__ qbf,    // 16384 x 256 bf16
    unsigned short* __restrict__ WTin,   // 256 x 512
    unsigned short* __restrict__ WTq,    // 256 x 256
    unsigned short* __restrict__ WTk,    // 256 x 256
    float* __restrict__ Wvw,             // 256 x 8
    float* __restrict__ bvw,             // 8
    float* __restrict__ logits,          // init to bout
    float* __restrict__ dent,            // [32][512] written directly
    float* __restrict__ denr)            // [32][512] written directly
{
    const int bid = blockIdx.x;
    const int t = threadIdx.x;

    if (bid < 1024) {            // ---- dentr: 16-row strips, heavy first ----
        const int b = bid >> 5;
        const int s16 = 31 - (bid & 31);   // heavy strips first
        const int q0 = s16 * 16;
        const int row = t >> 4;            // 16 rows per block
        const int lane16 = t & 15;
        const int qrow = q0 + row;
        const size_t base = ((size_t)(b * SEQ) + qrow) * SEQ;
        float dt = 0.f, dr = 0.f;
        for (int k4 = lane16 * 4; k4 <= qrow; k4 += 64) {
            float4 tv4 = *(const float4*)(tsp + base + k4);
            float4 rv4 = *(const float4*)(rel + base + k4);
            const float* tvp = &tv4.x;
            const float* rvp = &rv4.x;
            #pragma unroll
            for (int j = 0; j < 4; j++) {
                const bool va = (k4 + j) <= qrow;
                dt += va ? __expf(__expf(-fabsf(tvp[j]))) : 0.f;
                dr += (va && rvp[j] != 0.f) ? __expf(rvp[j]) : 0.f;
            }
        }
        dt += __shfl_xor(dt, 1); dt += __shfl_xor(dt, 2);
        dt += __shfl_xor(dt, 4); dt += __shfl_xor(dt, 8);
        dr += __shfl_xor(dr, 1); dr += __shfl_xor(dr, 2);
        dr += __shfl_xor(dr, 4); dr += __shfl_xor(dr, 8);
        if (lane16 == 0) {
            dent[b * SEQ + qrow] = dt;
            denr[b * SEQ + qrow] = dr;
        }
    } else if (bid < 5120) {     // ---- prep ----
        int r = (bid - 1024) * 4 + (t >> 6);
        int j = (t & 63) * 4;
        int item = item_inputs[r];
        int lab  = label_inputs[r];
        int qid  = item_ids[r];
        float4 e4 = *(const float4*)(embeds + (size_t)item * EMB + j);
        ushort4 on  = make_ushort4(f2bf(e4.x), f2bf(e4.y), f2bf(e4.z), f2bf(e4.w));
        ushort4 off = make_ushort4(0, 0, 0, 0);
        *(ushort4*)(Abig + (size_t)r * 512 + j)       = lab ? on : off;
        *(ushort4*)(Abig + (size_t)r * 512 + 256 + j) = lab ? off : on;
        float4 q4 = *(const float4*)(embeds + (size_t)qid * EMB + j);
        *(ushort4*)(qbf + (size_t)r * 256 + j) =
            make_ushort4(f2bf(q4.x), f2bf(q4.y), f2bf(q4.z), f2bf(q4.w));
    } else {                     // ---- wcombo ----
        int idx = (bid - 5120) * 256 + t;
        if (idx < 131072) {                       // WTin[n][k] = W_in[k][n], K=512
            int n = idx >> 9, k = idx & 511;
            WTin[idx] = f2bf(W_in[(size_t)k * 256 + n]);
        } else if (idx < 196608) {                // WTq
            int i = idx - 131072;
            int n = i >> 8, k = i & 255;
            WTq[i] = f2bf(Wq[(size_t)k * 256 + n]);
        } else if (idx < 262144) {                // WTk
            int i = idx - 196608;
            int n = i >> 8, k = i & 255;
            WTk[i] = f2bf(Wk[(size_t)k * 256 + n]);
        } else if (idx < 264192) {                // Wvw
            int i = idx - 262144;
            int c = i >> 3, h = i & 7;
            float s = 0.f;
            #pragma unroll
            for (int d = 0; d < 32; d++)
                s += Wv[(size_t)c * 256 + h * 32 + d] * Wout[h * 32 + d];
            Wvw[i] = s;
        } else if (idx < 264200) {                // bvw
            int h = idx - 264192;
            float s = 0.f;
            #pragma unroll
            for (int d = 0; d < 32; d++) s += bv[h * 32 + d] * Wout[h * 32 + d];
            bvw[h] = s;
        } else if (idx < 280584) {                // logits init = bout
            logits[idx - 264200] = bout[0];
        }
    }
}

// ---------------- MFMA GEMM body: C(M x 256) = A(M x KDIM) * BT^T + bias
template<int KDIM, int RELU, int OUTBF>
static __device__ __forceinline__ void gemm_body(
    const unsigned short* __restrict__ A,
    const unsigned short* __restrict__ BT,
    const float* __restrict__ bias,
    void* __restrict__ Cout, float scale)
{
    __shared__ unsigned short As[64][40];
    __shared__ unsigned short Bs[128][40];
    const int t = threadIdx.x;
    const int row0 = blockIdx.x * 64;
    const int col0 = blockIdx.y * 128;
    const int wid = t >> 6, lane = t & 63;
    const int wm = wid & 1, wn = wid >> 1;
    const int lg = lane >> 4, l15 = lane & 15;

    f32x4 acc[2][4];
    #pragma unroll
    for (int i = 0; i < 2; i++)
        #pragma unroll
        for (int j = 0; j < 4; j++) acc[i][j] = (f32x4){0.f, 0.f, 0.f, 0.f};

    const int arow = t >> 2, achk = t & 3;
    const int brow = t >> 1, bhalf = t & 1;

    for (int k0 = 0; k0 < KDIM; k0 += 32) {
        __syncthreads();
        *(uint4*)(&As[arow][achk * 8]) =
            *(const uint4*)(A + (size_t)(row0 + arow) * KDIM + k0 + achk * 8);
        const unsigned short* bsrc = BT + (size_t)(col0 + brow) * KDIM + k0 + bhalf * 16;
        *(uint4*)(&Bs[brow][bhalf * 16])     = *(const uint4*)(bsrc);
        *(uint4*)(&Bs[brow][bhalf * 16 + 8]) = *(const uint4*)(bsrc + 8);
        __syncthreads();
        bf16x8 af[2], bfr[4];
        #pragma unroll
        for (int fm = 0; fm < 2; fm++)
            af[fm] = *(const bf16x8*)(&As[wm * 32 + fm * 16 + l15][lg * 8]);
        #pragma unroll
        for (int fn = 0; fn < 4; fn++)
            bfr[fn] = *(const bf16x8*)(&Bs[wn * 64 + fn * 16 + l15][lg * 8]);
        #pragma unroll
        for (int fm = 0; fm < 2; fm++)
            #pragma unroll
            for (int fn = 0; fn < 4; fn++)
                acc[fm][fn] = __builtin_amdgcn_mfma_f32_16x16x32_bf16(
                    af[fm], bfr[fn], acc[fm][fn], 0, 0, 0);
    }
    #pragma unroll
    for (int fm = 0; fm < 2; fm++)
        #pragma unroll
        for (int fn = 0; fn < 4; fn++) {
            int col = col0 + wn * 64 + fn * 16 + l15;
            float bvv = bias[col];
            #pragma unroll
            for (int r = 0; r < 4; r++) {
                int row = row0 + wm * 32 + fm * 16 + lg * 4 + r;
                float v = acc[fm][fn][r] + bvv;
                if (RELU) v = fmaxf(v, 0.f);
                v *= scale;
                if (OUTBF) ((unsigned short*)Cout)[(size_t)row * 256 + col] = f2bf(v);
                else       ((float*)Cout)[(size_t)row * 256 + col] = v;
            }
        }
}

// ---------------- L2: X-GEMM (K=512, relu) || Q-GEMM (independent) via z
__global__ __launch_bounds__(256, 2) void gemmA_kernel(
    const unsigned short* __restrict__ Abig,
    const unsigned short* __restrict__ WTin,
    const float* __restrict__ b_in,
    unsigned short* __restrict__ Xbf,
    const unsigned short* __restrict__ qbf,
    const unsigned short* __restrict__ WTq,
    const float* __restrict__ bq,
    unsigned short* __restrict__ Qbf)
{
    if (blockIdx.z == 0)
        gemm_body<512, 1, 1>(Abig, WTin, b_in, (void*)Xbf, 1.0f);
    else
        gemm_body<256, 0, 1>(qbf, WTq, bq, (void*)Qbf, 0.17677669529663687f);
}

// ---------------- Vw body: Vw[row][h] = X[row]·Wvw[:,h] + bvw[h]
static __device__ __forceinline__ void vw_body(
    const unsigned short* __restrict__ Xbf,
    const float* __restrict__ Wvw,
    const float* __restrict__ bvw,
    float* __restrict__ Vw)
{
    __shared__ float sW[2048];
    __shared__ float sb[8];
    int t = threadIdx.x;
    #pragma unroll
    for (int i = 0; i < 8; i++) sW[i * 256 + t] = Wvw[i * 256 + t];
    if (t < 8) sb[t] = bvw[t];
    __syncthreads();
    int row = blockIdx.x * 256 + t;
    float acc[8];
    #pragma unroll
    for (int h = 0; h < 8; h++) acc[h] = sb[h];
    for (int d0 = 0; d0 < 32; d0++) {
        bf16x8 x = *(const bf16x8*)(Xbf + (size_t)row * 256 + d0 * 8);
        #pragma unroll
        for (int j = 0; j < 8; j++) {
            float xf = bf2f((unsigned short)x[j]);
            #pragma unroll
            for (int h = 0; h < 8; h++) acc[h] += xf * sW[(d0 * 8 + j) * 8 + h];
        }
    }
    *(float4*)(Vw + (size_t)row * 8)     = make_float4(acc[0], acc[1], acc[2], acc[3]);
    *(float4*)(Vw + (size_t)row * 8 + 4) = make_float4(acc[4], acc[5], acc[6], acc[7]);
}

// ---------------- L3: K-GEMM || Vw via z
__global__ __launch_bounds__(256, 2) void gemmB_kernel(
    const unsigned short* __restrict__ Xbf,
    const unsigned short* __restrict__ WTk,
    const float* __restrict__ bk,
    unsigned short* __restrict__ Kbf,
    const float* __restrict__ Wvw,
    const float* __restrict__ bvw,
    float* __restrict__ Vw)
{
    if (blockIdx.z == 0) {
        gemm_body<256, 0, 1>(Xbf, WTk, bk, (void*)Kbf, 1.0f);
    } else {
        if (blockIdx.x >= 64 || blockIdx.y != 0) return;
        vw_body(Xbf, Wvw, bvw, Vw);
    }
}

// ---------------- L4: attnW v6 — fused, bf16 sP for 8 blocks/CU occupancy
// grid 8192: id -> strip heavy-first (32) x b (32) x h (8); 256 threads = 4 waves
__global__ __launch_bounds__(256, 8) void attnW_kernel(
    const unsigned short* __restrict__ Qbf,
    const unsigned short* __restrict__ Kbf,
    const float* __restrict__ Vw,
    const float* __restrict__ rel,
    const float* __restrict__ tsp,
    const float* __restrict__ dent,
    const float* __restrict__ denr,
    const float* __restrict__ pl1,
    const float* __restrict__ pl2,
    float* __restrict__ logits,
    float* __restrict__ attn)
{
    __shared__ unsigned short sP[16][520];  // exp(score) bf16; 2-way alias max (free)
    __shared__ float sVw[512];
    __shared__ float sden[4][16];

    const int t = threadIdx.x;
    const int id = blockIdx.x;
    const int qt16 = 31 - (id >> 8);      // heavy strips dispatched first
    const int b = (id >> 3) & 31;
    const int h = id & 7;                 // h innermost: 8 neighbors share rel/ts rows
    const int q0 = qt16 * 16;
    const int qmax = q0 + 15;

    const int w = t >> 6, lane = t & 63;
    const int l15 = lane & 15, lg = lane >> 4;

    const float l1 = pl1[0], l2 = pl2[0];
    const float cp = (1.f - l1) * (1.f - l2);
    const float ct = (1.f - l1) * l2;
    const float cr = l1;

    // stage Vw column h for this b
    sVw[t]       = Vw[((size_t)(b * SEQ) + t) * 8 + h];
    sVw[256 + t] = Vw[((size_t)(b * SEQ) + 256 + t) * 8 + h];

    // Q fragment: rows q0+l15, dims h*32 + lg*8
    bf16x8 aq = *(const bf16x8*)(Qbf + (size_t)(b * SEQ + q0 + l15) * EMB + h * 32 + lg * 8);

    // ---- phase 1: MFMA scores -> exp -> sP (bf16); per-row den partials in f32 ----
    float dp[4] = {0.f, 0.f, 0.f, 0.f};
    #pragma unroll
    for (int ki = 0; ki < 4; ki++) {
        const int kt = w + ki * 4;        // wave-uniform tile index 0..15
        const int k0 = kt * 32;
        if (k0 <= qmax) {
            #pragma unroll
            for (int nf = 0; nf < 2; nf++) {
                const int kcol = k0 + nf * 16 + l15;
                bf16x8 bk = *(const bf16x8*)(Kbf +
                    (size_t)(b * SEQ + kcol) * EMB + h * 32 + lg * 8);
                f32x4 am = __builtin_amdgcn_mfma_f32_16x16x32_bf16(
                    aq, bk, (f32x4){0.f, 0.f, 0.f, 0.f}, 0, 0, 0);
                #pragma unroll
                for (int r = 0; r < 4; r++) {
                    const int qloc = lg * 4 + r;
                    float e = (kcol <= q0 + qloc) ? __expf(am[r]) : 0.f;
                    sP[qloc][kcol] = f2bf(e);
                    dp[r] += e;
                }
            }
        } else {
            #pragma unroll
            for (int nf = 0; nf < 2; nf++)
                #pragma unroll
                for (int r = 0; r < 4; r++)
                    sP[lg * 4 + r][k0 + nf * 16 + l15] = 0;
        }
    }
    #pragma unroll
    for (int r = 0; r < 4; r++) {
        float v = dp[r];
        v += __shfl_xor(v, 1); v += __shfl_xor(v, 2);
        v += __shfl_xor(v, 4); v += __shfl_xor(v, 8);
        if (l15 == 0) sden[w][lg * 4 + r] = v;
    }
    __syncthreads();

    // ---- phase 2: normalize + blend + nt write + logits ----
    const int wrow = t >> 4;
    const int wcol = (t & 15) * 4;
    const int qrow_w = q0 + wrow;
    const float den = sden[0][wrow] + sden[1][wrow] + sden[2][wrow] + sden[3][wrow];
    const float cpinv = cp / den;         // den>0: diagonal always valid
    const float dtv = dent[b * SEQ + qrow_w];
    const float drv = denr[b * SEQ + qrow_w];
    const float ctt = ct / dtv;
    const float crr = drv > 0.f ? cr / drv : 0.f;

    float* arow = attn + ((size_t)((b * NHEAD + h) * SEQ) + qrow_w) * SEQ;
    const size_t rbase = ((size_t)(b * SEQ) + qrow_w) * SEQ;
    const f32x4 z4 = (f32x4){0.f, 0.f, 0.f, 0.f};
    float plog = 0.f;

    #pragma unroll
    for (int s = 0; s < 8; s++) {
        const int c = wcol + s * 64;
        f32x4 o;
        if (c > qrow_w) {
            o = z4;
        } else {
            float4 tv4 = *(const float4*)(tsp + rbase + c);
            float4 rv4 = *(const float4*)(rel + rbase + c);
            ushort4 p4 = *(const ushort4*)(&sP[wrow][c]);
            const float* tvp = &tv4.x;
            const float* rvp = &rv4.x;
            const unsigned short* pp = &p4.x;
            #pragma unroll
            for (int j = 0; j < 4; j++) {
                const bool va = (c + j) <= qrow_w;
                float e_t = va ? __expf(__expf(-fabsf(tvp[j]))) * ctt : 0.f;
                float e_r = (va && rvp[j] != 0.f) ? __expf(rvp[j]) * crr : 0.f;
                float a = fmaf(bf2f(pp[j]), cpinv, e_t + e_r);  // sP=0 if invalid
                a = va ? a : 0.f;
                o[j] = a;
                plog = fmaf(a, sVw[c + j], plog);
            }
        }
        __builtin_nontemporal_store(o, (f32x4*)(arow + c));
    }

    // per-row logits: reduce over the 16 col-lanes, one atomic per row
    plog += __shfl_xor(plog, 1); plog += __shfl_xor(plog, 2);
    plog += __shfl_xor(plog, 4); plog += __shfl_xor(plog, 8);
    if ((t & 15) == 0)
        atomicAdd(&logits[b * SEQ + qrow_w], plog);
}

// ---------------- host launch ----------------
extern "C" void kernel_launch(void* const* d_in, const int* in_sizes, int n_in,
                              void* d_out, int out_size, void* d_ws, size_t ws_size,
                              hipStream_t stream)
{
    (void)in_sizes; (void)n_in; (void)out_size; (void)ws_size;
    const int*   item_inputs  = (const int*)d_in[0];
    const int*   label_inputs = (const int*)d_in[1];
    const int*   item_ids     = (const int*)d_in[2];
    const float* rel   = (const float*)d_in[3];
    const float* tsp   = (const float*)d_in[4];
    const float* emb   = (const float*)d_in[5];
    const float* W_in  = (const float*)d_in[6];
    const float* b_in  = (const float*)d_in[7];
    const float* Wq    = (const float*)d_in[8];
    const float* bq    = (const float*)d_in[9];
    const float* Wk    = (const float*)d_in[10];
    const float* bk    = (const float*)d_in[11];
    const float* Wv    = (const float*)d_in[12];
    const float* bv    = (const float*)d_in[13];
    const float* Wout  = (const float*)d_in[14];
    const float* bout  = (const float*)d_in[15];
    const float* l1    = (const float*)d_in[16];
    const float* l2    = (const float*)d_in[17];

    const size_t R = 16384;
    char* w = (char*)d_ws;
    unsigned short* Abig = (unsigned short*)w; w += R * 512 * 2;
    unsigned short* qbf  = (unsigned short*)w; w += R * 256 * 2;
    unsigned short* WTin = (unsigned short*)w; w += (size_t)256 * 512 * 2;
    unsigned short* WTq  = (unsigned short*)w; w += (size_t)256 * 256 * 2;
    unsigned short* WTk  = (unsigned short*)w; w += (size_t)256 * 256 * 2;
    unsigned short* Xbf  = (unsigned short*)w; w += R * 256 * 2;
    unsigned short* Qbf  = (unsigned short*)w; w += R * 256 * 2;
    unsigned short* Kbf  = (unsigned short*)w; w += R * 256 * 2;
    float* Wvw  = (float*)w; w += 2048 * 4;
    float* Vw   = (float*)w; w += R * 8 * 4;
    float* bvw  = (float*)w; w += 256;          // 8 floats + pad
    float* dent = (float*)w; w += (size_t)32 * SEQ * 4;           // 64 KB
    float* denr = (float*)w; w += (size_t)32 * SEQ * 4;           // 64 KB

    float* logits = (float*)d_out;
    float* attnp  = (float*)d_out + 16384;

    // L1: dentr (first, heavy) || prep || wcombo (+logits init)
    fused_prep_kernel<<<dim3(6217), dim3(256), 0, stream>>>(
        item_inputs, label_inputs, item_ids, emb,
        W_in, Wq, Wk, Wv, Wout, bv, bout, rel, tsp,
        Abig, qbf, WTin, WTq, WTk, Wvw, bvw, logits, dent, denr);

    // L2: X-GEMM || Q-GEMM
    gemmA_kernel<<<dim3(256, 2, 2), dim3(256), 0, stream>>>(
        Abig, WTin, b_in, Xbf, qbf, WTq, bq, Qbf);

    // L3: K-GEMM || Vw
    gemmB_kernel<<<dim3(256, 2, 2), dim3(256), 0, stream>>>(
        Xbf, WTk, bk, Kbf, Wvw, bvw, Vw);

    // L4: fully fused attention (scores+den+blend+write+logits)
    attnW_kernel<<<dim3(8192), dim3(256), 0, stream>>>(
        Qbf, Kbf, Vw, rel, tsp, dent, denr, l1, l2, logits, attnp);
}